// Round 15
// baseline (209.778 us; speedup 1.0000x reference)
//
#include <hip/hip_runtime.h>
#include <hip/hip_bf16.h>

#define B_  2
#define S_  2048
#define D_  1024
#define H_  16
#define HD_ 64
#define SCALE_ 0.03125f   // 1/sqrt(1024), exact power of two
#define LOG2E_ 1.4426950408889634f
// Q is pre-scaled by SCALE_*LOG2E_ so attention can use exp2 directly.
#define QSCALE_ (SCALE_ * LOG2E_)

typedef __bf16 bf16;
typedef __attribute__((ext_vector_type(8))) __bf16 bf16x8;
typedef __attribute__((ext_vector_type(8))) unsigned short u16x8;
typedef __attribute__((ext_vector_type(4))) __bf16 bf16x4;
typedef __attribute__((ext_vector_type(4))) float f32x4;
typedef __attribute__((ext_vector_type(4))) unsigned int u32x4;

__device__ __forceinline__ void gload_lds16(const void* g, void* l) {
  __builtin_amdgcn_global_load_lds(
      (const __attribute__((address_space(1))) unsigned int*)g,
      (__attribute__((address_space(3))) unsigned int*)l,
      16, 0, 0);
}

__device__ __forceinline__ bf16x8 load8(const float* p) {
  const float4 a = *(const float4*)p;
  const float4 b = *(const float4*)(p + 4);
  bf16x8 r;
  r[0] = (bf16)a.x; r[1] = (bf16)a.y; r[2] = (bf16)a.z; r[3] = (bf16)a.w;
  r[4] = (bf16)b.x; r[5] = (bf16)b.y; r[6] = (bf16)b.z; r[7] = (bf16)b.w;
  return r;
}
__device__ __forceinline__ bf16x8 load8(const bf16* p) {
  return *(const bf16x8*)p;
}

// ---------------------------------------------------------------------------
// Weight conversion: Wq|Wk|Wv|Wo fp32 -> one contiguous bf16 buffer (4 Mi el).
// (mid tier only)
// ---------------------------------------------------------------------------
__global__ __launch_bounds__(256)
void wconv_kernel(const float* __restrict__ Wq, const float* __restrict__ Wk,
                  const float* __restrict__ Wv, const float* __restrict__ Wo,
                  bf16* __restrict__ dst)
{
  const int n4  = (blockIdx.x * 256 + threadIdx.x) * 4;
  const int m   = n4 >> 20;
  const int off = n4 & ((1 << 20) - 1);
  const float* src = m == 0 ? Wq : (m == 1 ? Wk : (m == 2 ? Wv : Wo));
  const float4 a = *(const float4*)(src + off);
  bf16x4 o = {(bf16)a.x, (bf16)a.y, (bf16)a.z, (bf16)a.w};
  *(bf16x4*)(dst + n4) = o;
}

// ---------------------------------------------------------------------------
// TOP-TIER conversion: weights (4 Mi el) + q/k/v activations (12 Mi el) ->
// bf16. dst layout (elements): [0,4Mi)=Wq|Wk|Wv|Wo, [4Mi,8Mi)=Qp (skipped),
// [8,12)=q, [12,16)=k, [16,20)=v. grid 16384 x 256, 4 el/thread.
// ---------------------------------------------------------------------------
__global__ __launch_bounds__(256)
void conv_kernel(const float* __restrict__ Wq, const float* __restrict__ Wk,
                 const float* __restrict__ Wv, const float* __restrict__ Wo,
                 const float* __restrict__ q, const float* __restrict__ k,
                 const float* __restrict__ v, bf16* __restrict__ dst)
{
  const size_t MI = (size_t)1 << 20;
  const size_t n4 = ((size_t)blockIdx.x * 256 + threadIdx.x) * 4;
  const float* src;
  size_t so, dof;
  if (n4 < 4 * MI) {                       // weights
    const int m = (int)(n4 >> 20);
    src = m == 0 ? Wq : (m == 1 ? Wk : (m == 2 ? Wv : Wo));
    so  = n4 & (MI - 1);
    dof = n4;
  } else {                                  // activations
    const size_t a = n4 - 4 * MI;           // [0, 12Mi)
    const int m = (int)(a >> 22);           // 4 Mi el per activation
    src = m == 0 ? q : (m == 1 ? k : v);
    so  = a & (4 * MI - 1);
    dof = n4 + 4 * MI;                      // skip the Qp region
  }
  const float4 a4 = *(const float4*)(src + so);
  bf16x4 o = {(bf16)a4.x, (bf16)a4.y, (bf16)a4.z, (bf16)a4.w};
  *(bf16x4*)(dst + dof) = o;
}

// ---------------------------------------------------------------------------
// TOP-TIER QKV projection (round-5 exact, best measured): pure-m97 128x128,
// BOTH operands bf16 via global_load_lds. grid (32, 24).
// ---------------------------------------------------------------------------
__global__ __launch_bounds__(256, 2)
void gemm_qkv3_kernel(const bf16* __restrict__ Ab, const bf16* __restrict__ Wb,
                      bf16* __restrict__ Cq, bf16* __restrict__ Ck,
                      bf16* __restrict__ Cv)
{
  __shared__ bf16 lA[128 * 32];
  __shared__ bf16 lB[128 * 32];

  const int sel = blockIdx.y >> 3;
  const int bn  = blockIdx.y & 7;
  const bf16* A  = Ab + ((size_t)sel << 22);
  const bf16* Bw = Wb + ((size_t)sel << 20);
  bf16*       C  = sel == 0 ? Cq : (sel == 1 ? Ck : Cv);
  const float scale = sel == 0 ? QSCALE_ : 1.0f;

  const int t    = threadIdx.x;
  const int wave = t >> 6;
  const int lane = t & 63;
  const int quad = lane >> 4;
  const int l16  = lane & 15;
  const int bm = blockIdx.x;
  const int wm = (wave >> 1) * 64;
  const int wn = (wave & 1) * 64;

  const int srow = t >> 2;
  const int scol = (t & 3) * 8;
  const bf16* gA = A  + (size_t)(bm * 128 + srow) * D_ + scol;
  const bf16* gB = Bw + (size_t)(bn * 128 + srow) * D_ + scol;

  f32x4 acc[4][4] = {};

  for (int k0 = 0; k0 < D_; k0 += 32) {
    __syncthreads();
    gload_lds16(gA,                   (char*)lA + wave * 1024);
    gload_lds16(gA + (size_t)64 * D_, (char*)lA + 4096 + wave * 1024);
    gload_lds16(gB,                   (char*)lB + wave * 1024);
    gload_lds16(gB + (size_t)64 * D_, (char*)lB + 4096 + wave * 1024);
    __syncthreads();

    bf16x8 af[4], bfr[4];
#pragma unroll
    for (int i = 0; i < 4; ++i) {
      af[i]  = *(const bf16x8*)(lA + (wm + i * 16 + l16) * 32 + quad * 8);
      bfr[i] = *(const bf16x8*)(lB + (wn + i * 16 + l16) * 32 + quad * 8);
    }
#pragma unroll
    for (int mi = 0; mi < 4; ++mi)
#pragma unroll
      for (int ni = 0; ni < 4; ++ni)
        acc[mi][ni] = __builtin_amdgcn_mfma_f32_16x16x32_bf16(
            af[mi], bfr[ni], acc[mi][ni], 0, 0, 0);

    gA += 32;
    gB += 32;
  }

#pragma unroll
  for (int mi = 0; mi < 4; ++mi) {
#pragma unroll
    for (int ni = 0; ni < 4; ++ni) {
      const int col = bn * 128 + wn + ni * 16 + l16;
#pragma unroll
      for (int r = 0; r < 4; ++r) {
        const int row = bm * 128 + wm + mi * 16 + quad * 4 + r;
        C[(size_t)row * D_ + col] = (bf16)(acc[mi][ni][r] * scale);
      }
    }
  }
}

// ---------------------------------------------------------------------------
// MID-TIER QKV projection: A fp32 (reg-staged + cvt) with cross-iteration
// register prefetch, W bf16 via global_load_lds. grid (32, 24).
// ---------------------------------------------------------------------------
__global__ __launch_bounds__(256, 2)
void gemm_qkv_b_kernel(const float* __restrict__ Aq, const float* __restrict__ Ak,
                       const float* __restrict__ Av, const bf16* __restrict__ Wb,
                       bf16* __restrict__ Cq, bf16* __restrict__ Ck,
                       bf16* __restrict__ Cv)
{
  __shared__ bf16 lA[128 * 32];
  __shared__ bf16 lB[128 * 32];

  const int sel = blockIdx.y >> 3;
  const int bn  = blockIdx.y & 7;
  const float* A  = sel == 0 ? Aq : (sel == 1 ? Ak : Av);
  const bf16*  Bw = Wb + ((size_t)sel << 20);
  bf16*        C  = sel == 0 ? Cq : (sel == 1 ? Ck : Cv);
  const float scale = sel == 0 ? QSCALE_ : 1.0f;

  const int t    = threadIdx.x;
  const int wave = t >> 6;
  const int lane = t & 63;
  const int quad = lane >> 4;
  const int l16  = lane & 15;
  const int bm = blockIdx.x;
  const int wm = (wave >> 1) * 64;
  const int wn = (wave & 1) * 64;

  const int srow = t >> 2;
  const int scol = (t & 3) * 8;
  const float* gA  = A  + (size_t)(bm * 128 + srow) * D_ + scol;
  const bf16*  gBb = Bw + (size_t)(bn * 128 + srow) * D_ + scol;

  f32x4 acc[4][4] = {};

  bf16x8 a0 = load8(gA);
  bf16x8 a1 = load8(gA + (size_t)64 * D_);

  for (int k0 = 0; k0 < D_; k0 += 32) {
    __syncthreads();
    *(bf16x8*)(lA + srow * 32 + scol)        = a0;
    *(bf16x8*)(lA + (srow + 64) * 32 + scol) = a1;
    gload_lds16(gBb,                   (char*)lB + wave * 1024);
    gload_lds16(gBb + (size_t)64 * D_, (char*)lB + 4096 + wave * 1024);
    gBb += 32;
    __syncthreads();

    if (k0 + 32 < D_) {     // prefetch next A tile during the MFMA phase
      gA += 32;
      a0 = load8(gA);
      a1 = load8(gA + (size_t)64 * D_);
    }

    bf16x8 af[4], bfr[4];
#pragma unroll
    for (int i = 0; i < 4; ++i) {
      af[i]  = *(const bf16x8*)(lA + (wm + i * 16 + l16) * 32 + quad * 8);
      bfr[i] = *(const bf16x8*)(lB + (wn + i * 16 + l16) * 32 + quad * 8);
    }
#pragma unroll
    for (int mi = 0; mi < 4; ++mi)
#pragma unroll
      for (int ni = 0; ni < 4; ++ni)
        acc[mi][ni] = __builtin_amdgcn_mfma_f32_16x16x32_bf16(
            af[mi], bfr[ni], acc[mi][ni], 0, 0, 0);
  }

#pragma unroll
  for (int mi = 0; mi < 4; ++mi) {
#pragma unroll
    for (int ni = 0; ni < 4; ++ni) {
      const int col = bn * 128 + wn + ni * 16 + l16;
#pragma unroll
      for (int r = 0; r < 4; ++r) {
        const int row = bm * 128 + wm + mi * 16 + quad * 4 + r;
        C[(size_t)row * D_ + col] = (bf16)(acc[mi][ni][r] * scale);
      }
    }
  }
}

// ---------------------------------------------------------------------------
// FAST output projection (round-5 exact): ctx bf16 + Wo bf16 via
// global_load_lds, fp32 output + bias. Tile 128x64, grid (32, 16).
// ---------------------------------------------------------------------------
__global__ __launch_bounds__(256, 2)
void gemm_out_b_kernel(const bf16* __restrict__ A, const bf16* __restrict__ Bw,
                       const float* __restrict__ bias, float* __restrict__ C)
{
  __shared__ bf16 lA[128 * 32];
  __shared__ bf16 lB[64 * 32];

  const int t    = threadIdx.x;
  const int wave = t >> 6;
  const int lane = t & 63;
  const int quad = lane >> 4;
  const int l16  = lane & 15;
  const int bm = blockIdx.x;
  const int bn = blockIdx.y;
  const int wm = wave * 32;

  const int srow = t >> 2;
  const int scol = (t & 3) * 8;
  const bf16* gA = A  + (size_t)(bm * 128 + srow) * D_ + scol;
  const bf16* gB = Bw + (size_t)(bn * 64 + srow) * D_ + scol;

  f32x4 acc[2][4] = {};

  for (int k0 = 0; k0 < D_; k0 += 32) {
    __syncthreads();
    gload_lds16(gA,                   (char*)lA + wave * 1024);
    gload_lds16(gA + (size_t)64 * D_, (char*)lA + 4096 + wave * 1024);
    gload_lds16(gB,                   (char*)lB + wave * 1024);
    __syncthreads();

    bf16x8 af[2], bfr[4];
#pragma unroll
    for (int i = 0; i < 2; ++i)
      af[i]  = *(const bf16x8*)(lA + (wm + i * 16 + l16) * 32 + quad * 8);
#pragma unroll
    for (int i = 0; i < 4; ++i)
      bfr[i] = *(const bf16x8*)(lB + (i * 16 + l16) * 32 + quad * 8);
#pragma unroll
    for (int mi = 0; mi < 2; ++mi)
#pragma unroll
      for (int ni = 0; ni < 4; ++ni)
        acc[mi][ni] = __builtin_amdgcn_mfma_f32_16x16x32_bf16(
            af[mi], bfr[ni], acc[mi][ni], 0, 0, 0);

    gA += 32;
    gB += 32;
  }

  float bv[4];
#pragma unroll
  for (int ni = 0; ni < 4; ++ni)
    bv[ni] = bias[bn * 64 + ni * 16 + l16];
#pragma unroll
  for (int mi = 0; mi < 2; ++mi) {
#pragma unroll
    for (int ni = 0; ni < 4; ++ni) {
      const int col = bn * 64 + ni * 16 + l16;
#pragma unroll
      for (int r = 0; r < 4; ++r) {
        const int row = bm * 128 + wm + mi * 16 + quad * 4 + r;
        C[(size_t)row * D_ + col] = acc[mi][ni][r] + bv[ni];
      }
    }
  }
}

// ---------------------------------------------------------------------------
// FALLBACK QKV projection (ws < 16 MiB): fp32 weights, QSCALE_ fold on Q.
// ---------------------------------------------------------------------------
__global__ __launch_bounds__(256, 2)
void gemm_qkv_kernel(const float* __restrict__ Aq, const float* __restrict__ Ak,
                     const float* __restrict__ Av, const float* __restrict__ Wq,
                     const float* __restrict__ Wk, const float* __restrict__ Wv,
                     bf16* __restrict__ Cq, bf16* __restrict__ Ck,
                     bf16* __restrict__ Cv)
{
  __shared__ bf16 lA[128 * 32];
  __shared__ bf16 lB[128 * 32];

  const int sel = blockIdx.y >> 3;
  const int bn  = blockIdx.y & 7;
  const float* A  = sel == 0 ? Aq : (sel == 1 ? Ak : Av);
  const float* Bw = sel == 0 ? Wq : (sel == 1 ? Wk : Wv);
  bf16*        C  = sel == 0 ? Cq : (sel == 1 ? Ck : Cv);
  const float scale = sel == 0 ? QSCALE_ : 1.0f;

  const int t    = threadIdx.x;
  const int wave = t >> 6;
  const int lane = t & 63;
  const int quad = lane >> 4;
  const int l16  = lane & 15;
  const int bm = blockIdx.x;
  const int wm = (wave >> 1) * 64;
  const int wn = (wave & 1) * 64;

  const int srow = t >> 2;
  const int scol = (t & 3) * 8;
  const float* gA = A  + (size_t)(bm * 128 + srow) * D_ + scol;
  const float* gB = Bw + (size_t)(bn * 128 + srow) * D_ + scol;

  f32x4 acc[4][4] = {};

  for (int k0 = 0; k0 < D_; k0 += 32) {
    const bf16x8 a0 = load8(gA);
    const bf16x8 a1 = load8(gA + (size_t)64 * D_);
    const bf16x8 b0 = load8(gB);
    const bf16x8 b1 = load8(gB + (size_t)64 * D_);

    __syncthreads();
    *(bf16x8*)(lA + srow * 32 + scol)        = a0;
    *(bf16x8*)(lA + (srow + 64) * 32 + scol) = a1;
    *(bf16x8*)(lB + srow * 32 + scol)        = b0;
    *(bf16x8*)(lB + (srow + 64) * 32 + scol) = b1;
    __syncthreads();

    bf16x8 af[4], bfr[4];
#pragma unroll
    for (int i = 0; i < 4; ++i) {
      af[i]  = *(const bf16x8*)(lA + (wm + i * 16 + l16) * 32 + quad * 8);
      bfr[i] = *(const bf16x8*)(lB + (wn + i * 16 + l16) * 32 + quad * 8);
    }
#pragma unroll
    for (int mi = 0; mi < 4; ++mi)
#pragma unroll
      for (int ni = 0; ni < 4; ++ni)
        acc[mi][ni] = __builtin_amdgcn_mfma_f32_16x16x32_bf16(
            af[mi], bfr[ni], acc[mi][ni], 0, 0, 0);

    gA += 32;
    gB += 32;
  }

#pragma unroll
  for (int mi = 0; mi < 4; ++mi) {
#pragma unroll
    for (int ni = 0; ni < 4; ++ni) {
      const int col = bn * 128 + wn + ni * 16 + l16;
#pragma unroll
      for (int r = 0; r < 4; ++r) {
        const int row = bm * 128 + wm + mi * 16 + quad * 4 + r;
        C[(size_t)row * D_ + col] = (bf16)(acc[mi][ni][r] * scale);
      }
    }
  }
}

// ---------------------------------------------------------------------------
// FALLBACK output projection (ws < 16 MiB): fp32 weights. Tile 128x64.
// ---------------------------------------------------------------------------
__global__ __launch_bounds__(256, 2)
void gemm_out_kernel(const bf16* __restrict__ A, const float* __restrict__ Bw,
                     const float* __restrict__ bias, float* __restrict__ C)
{
  __shared__ bf16 lA[128 * 32];
  __shared__ bf16 lB[64 * 32];

  const int t    = threadIdx.x;
  const int wave = t >> 6;
  const int lane = t & 63;
  const int quad = lane >> 4;
  const int l16  = lane & 15;
  const int bm = blockIdx.x;
  const int bn = blockIdx.y;
  const int wm = wave * 32;

  const int srow = t >> 2;
  const int scol = (t & 3) * 8;
  const bf16*  gA = A  + (size_t)(bm * 128 + srow) * D_ + scol;
  const float* gB = Bw + (size_t)(bn * 64 + srow) * D_ + scol;

  f32x4 acc[2][4] = {};

  for (int k0 = 0; k0 < D_; k0 += 32) {
    const bf16x8 a0 = load8(gA);
    const bf16x8 a1 = load8(gA + (size_t)64 * D_);
    const bf16x8 b0 = load8(gB);

    __syncthreads();
    *(bf16x8*)(lA + srow * 32 + scol)        = a0;
    *(bf16x8*)(lA + (srow + 64) * 32 + scol) = a1;
    *(bf16x8*)(lB + srow * 32 + scol)        = b0;
    __syncthreads();

    bf16x8 af[2], bfr[4];
#pragma unroll
    for (int i = 0; i < 2; ++i)
      af[i]  = *(const bf16x8*)(lA + (wm + i * 16 + l16) * 32 + quad * 8);
#pragma unroll
    for (int i = 0; i < 4; ++i)
      bfr[i] = *(const bf16x8*)(lB + (i * 16 + l16) * 32 + quad * 8);
#pragma unroll
    for (int mi = 0; mi < 2; ++mi)
#pragma unroll
      for (int ni = 0; ni < 4; ++ni)
        acc[mi][ni] = __builtin_amdgcn_mfma_f32_16x16x32_bf16(
            af[mi], bfr[ni], acc[mi][ni], 0, 0, 0);

    gA += 32;
    gB += 32;
  }

  float bv[4];
#pragma unroll
  for (int ni = 0; ni < 4; ++ni)
    bv[ni] = bias[bn * 64 + ni * 16 + l16];
#pragma unroll
  for (int mi = 0; mi < 2; ++mi) {
#pragma unroll
    for (int ni = 0; ni < 4; ++ni) {
      const int col = bn * 64 + ni * 16 + l16;
#pragma unroll
      for (int r = 0; r < 4; ++r) {
        const int row = bm * 128 + wm + mi * 16 + quad * 4 + r;
        C[(size_t)row * D_ + col] = acc[mi][ni][r] + bv[ni];
      }
    }
  }
}

// ---------------------------------------------------------------------------
// Flash attention v8 — EXACT round-11 version (best measured: attn 52.9 us,
// total 206.9 us). Round-12 (+setprio+perm) and round-13 (+perm only) both
// regressed (~55.5 us); both reverted.
//  - In-register P via cvt_pk + permlane butterfly (no lP buffer/fence):
//    after swapped QK^T, lane (quad,l16) holds P[l16][16nt+4q+r]; pack pairs
//    with v_cvt_pk_bf16_f32, then permlane32+permlane16 swaps deliver the
//    PV A-fragments in-register. Removes 12 DS instrs + 1 barrier per iter.
//  - SWAPPED QK^T; per-lane denominator; reg prefetch of next K/V tile.
// grid (16, 32) = 512 blocks = 2/CU; LDS 36 KiB.
// ---------------------------------------------------------------------------
__global__ __launch_bounds__(256, 2)
void attn_kernel(const bf16* Q, const bf16* __restrict__ K,
                 const bf16* __restrict__ V, bf16* O)
{
  __shared__ bf16 lQ[128 * 72];
  __shared__ bf16 lK[64 * 72];
  __shared__ bf16 lVT[64 * 72];

  const int t    = threadIdx.x;
  const int wave = t >> 6;
  const int lane = t & 63;
  const int quad = lane >> 4;
  const int l16  = lane & 15;

  // XCD swizzle: flat bits [2:0]=xcd, [6:3]=qt, [8:7]=head-within-xcd
  const int flat = blockIdx.y * 16 + blockIdx.x;
  const int qt   = (flat >> 3) & 15;
  const int bh   = (flat & 7) * 4 + (flat >> 7);
  const size_t headoff =
      (size_t)(bh >> 4) * ((size_t)S_ * D_) + (size_t)(bh & 15) * HD_;

  // ---- stage Q tile (128 rows)
  const int sr  = t >> 3;          // 0..31
  const int scx = (t & 7) * 8;
#pragma unroll
  for (int i = 0; i < 4; ++i) {
    const bf16x8 qv =
        *(const bf16x8*)(Q + headoff + (size_t)(qt * 128 + sr + 32 * i) * D_ + scx);
    *(bf16x8*)(lQ + (sr + 32 * i) * 72 + scx) = qv;
  }
  __syncthreads();

  // Q fragments (B-operand of swapped QK^T): lane's l16 picks the q-row.
  bf16x8 qf[2][2];
#pragma unroll
  for (int m = 0; m < 2; ++m)
#pragma unroll
    for (int ks = 0; ks < 2; ++ks)
      qf[m][ks] = *(const bf16x8*)(lQ + (wave * 32 + m * 16 + l16) * 72 +
                                   (ks * 4 + quad) * 8);

  f32x4 acco[2][4] = {};
  float den[2] = {0.f, 0.f};

  const int dp = t & 31;    // d-pair index: columns 2dp, 2dp+1
  const int kg = t >> 5;    // key group: keys kg*8 .. kg*8+7

  // ---- prefetch registers
  bf16x8 pk0, pk1;
  unsigned int pv[8];
  {
    const bf16* kb = K + headoff + (size_t)sr * D_ + scx;        // kt = 0
    pk0 = load8(kb);
    pk1 = load8(kb + (size_t)32 * D_);
    const bf16* vb = V + headoff + (size_t)(kg * 8) * D_ + 2 * dp;
#pragma unroll
    for (int j = 0; j < 8; ++j)
      pv[j] = *(const unsigned int*)(vb + (size_t)j * D_);
  }

  for (int kt = 0; kt < S_ / 64; ++kt) {
    __syncthreads();   // prev iteration's lK/lVT reads done

    // ---- commit prefetched K tile
    *(bf16x8*)(lK + sr * 72 + scx)        = pk0;
    *(bf16x8*)(lK + (sr + 32) * 72 + scx) = pk1;
    // ---- commit prefetched V (transposed): rows 2dp, 2dp+1, keys kg*8..+7
    {
      u16x8 w0, w1;
#pragma unroll
      for (int j = 0; j < 8; ++j) {
        w0[j] = (unsigned short)(pv[j] & 0xffffu);
        w1[j] = (unsigned short)(pv[j] >> 16);
      }
      *(u16x8*)(lVT + (2 * dp) * 72 + kg * 8)     = w0;
      *(u16x8*)(lVT + (2 * dp + 1) * 72 + kg * 8) = w1;
    }
    __syncthreads();   // staging visible

    // ---- prefetch next iteration (in flight during compute)
    if (kt + 1 < S_ / 64) {
      const bf16* kb = K + headoff + (size_t)((kt + 1) * 64 + sr) * D_ + scx;
      pk0 = load8(kb);
      pk1 = load8(kb + (size_t)32 * D_);
      const bf16* vb = V + headoff + (size_t)((kt + 1) * 64 + kg * 8) * D_ + 2 * dp;
#pragma unroll
      for (int j = 0; j < 8; ++j)
        pv[j] = *(const unsigned int*)(vb + (size_t)j * D_);
    }

    // ---- S^T = K Q^T  (Q pre-scaled; kf reused across both m-halves)
    f32x4 sc[2][4] = {};
#pragma unroll
    for (int nt = 0; nt < 4; ++nt) {
#pragma unroll
      for (int ks = 0; ks < 2; ++ks) {
        const bf16x8 kf =
            *(const bf16x8*)(lK + (nt * 16 + l16) * 72 + (ks * 4 + quad) * 8);
#pragma unroll
        for (int m = 0; m < 2; ++m)
          sc[m][nt] = __builtin_amdgcn_mfma_f32_16x16x32_bf16(
              kf, qf[m][ks], sc[m][nt], 0, 0, 0);
      }
    }

    // ---- p = exp2(s); pack to bf16 words; permlane butterfly -> pf in regs
    bf16x8 pf[2][2];
#pragma unroll
    for (int m = 0; m < 2; ++m) {
      unsigned int W[4][2];      // [nt][j], fully static indexing
#pragma unroll
      for (int nt = 0; nt < 4; ++nt) {
        const float p0 = __builtin_amdgcn_exp2f(sc[m][nt][0]);
        const float p1 = __builtin_amdgcn_exp2f(sc[m][nt][1]);
        const float p2 = __builtin_amdgcn_exp2f(sc[m][nt][2]);
        const float p3 = __builtin_amdgcn_exp2f(sc[m][nt][3]);
        den[m] += (p0 + p1) + (p2 + p3);
        asm("v_cvt_pk_bf16_f32 %0, %1, %2" : "=v"(W[nt][0]) : "v"(p0), "v"(p1));
        asm("v_cvt_pk_bf16_f32 %0, %1, %2" : "=v"(W[nt][1]) : "v"(p2), "v"(p3));
      }
#pragma unroll
      for (int ks = 0; ks < 2; ++ks) {
        unsigned int r0 = W[2 * ks][0], s0 = W[2 * ks + 1][0];
        unsigned int r1 = W[2 * ks][1], s1 = W[2 * ks + 1][1];
        asm("v_permlane32_swap_b32 %0, %1" : "+v"(r0), "+v"(s0));
        asm("v_permlane16_swap_b32 %0, %1" : "+v"(r0), "+v"(s0));
        asm("v_permlane32_swap_b32 %0, %1" : "+v"(r1), "+v"(s1));
        asm("v_permlane16_swap_b32 %0, %1" : "+v"(r1), "+v"(s1));
        const u32x4 pw = {r0, r1, s0, s1};   // words w0,w1,w2,w3
        pf[m][ks] = __builtin_bit_cast(bf16x8, pw);
      }
    }

    // ---- O += P V  (vf reused across both m-halves; pf from registers)
#pragma unroll
    for (int dt = 0; dt < 4; ++dt) {
#pragma unroll
      for (int ks = 0; ks < 2; ++ks) {
        const bf16x8 vf =
            *(const bf16x8*)(lVT + (dt * 16 + l16) * 72 + (ks * 4 + quad) * 8);
#pragma unroll
        for (int m = 0; m < 2; ++m)
          acco[m][dt] = __builtin_amdgcn_mfma_f32_16x16x32_bf16(
              pf[m][ks], vf, acco[m][dt], 0, 0, 0);
      }
    }
  }

  // ---- epilogue: finish denominator (sum the 4 key-quads), normalize, store
#pragma unroll
  for (int m = 0; m < 2; ++m) {
    den[m] += __shfl_xor(den[m], 16);
    den[m] += __shfl_xor(den[m], 32);
  }
#pragma unroll
  for (int m = 0; m < 2; ++m) {
#pragma unroll
    for (int r = 0; r < 4; ++r) {
      const float rd  = 1.f / __shfl(den[m], quad * 4 + r);
      const int   row = qt * 128 + wave * 32 + m * 16 + quad * 4 + r;
#pragma unroll
      for (int dt = 0; dt < 4; ++dt)
        O[headoff + (size_t)row * D_ + dt * 16 + l16] =
            (bf16)(acco[m][dt][r] * rd);
    }
  }
}

// ---------------------------------------------------------------------------
// Tiers:
//  ws >= 40 MiB: conv (W + q/k/v -> bf16), pure-bf16 QKV GEMM (128x128),
//                attn v8 (in-register P), out (128x64).
//                ws: Wb[0,8MiB) Qp[8,16) Aq[16,24) Ak[24,32) Av[32,40).
//  ws >= 16 MiB: wconv + fp32-A reg-prefetch QKV, attn, out.
//  else:         fp32-weight fallback.
// K'/V' live in d_out (bf16 view); final GEMM overwrites d_out with fp32.
// ---------------------------------------------------------------------------
extern "C" void kernel_launch(void* const* d_in, const int* in_sizes, int n_in,
                              void* d_out, int out_size, void* d_ws, size_t ws_size,
                              hipStream_t stream)
{
  const float* q  = (const float*)d_in[0];
  const float* k  = (const float*)d_in[1];
  const float* v  = (const float*)d_in[2];
  const float* Wq = (const float*)d_in[3];
  const float* Wk = (const float*)d_in[4];
  const float* Wv = (const float*)d_in[5];
  const float* Wo = (const float*)d_in[6];
  const float* bo = (const float*)d_in[7];
  float* outf = (float*)d_out;
  bf16*  outs = (bf16*)d_out;
  bf16*  wsb  = (bf16*)d_ws;

  const size_t MD = (size_t)B_ * S_ * D_;   // 4 Mi elements

  dim3 blk(256);
  dim3 gqkv(B_ * S_ / 128, 24);
  dim3 gattn(S_ / 128, B_ * H_);
  dim3 gout(B_ * S_ / 128, D_ / 64);

  bf16* Kp = outs;          // d_out [0, 8Mi)
  bf16* Vp = outs + MD;     // d_out [8Mi, 16Mi)

  if (ws_size >= (size_t)40 << 20) {
    bf16* Wb = wsb;            // [0, 4Mi el): Wq|Wk|Wv|Wo bf16
    bf16* Qp = wsb + MD;       // [4Mi, 8Mi el): Q' -> ctx in place
    bf16* Ab = wsb + 2 * MD;   // [8Mi, 20Mi el): q|k|v bf16

    conv_kernel<<<16384, blk, 0, stream>>>(Wq, Wk, Wv, Wo, q, k, v, wsb);
    gemm_qkv3_kernel<<<gqkv, blk, 0, stream>>>(Ab, Wb, Qp, Kp, Vp);
    attn_kernel<<<gattn, blk, 0, stream>>>(Qp, Kp, Vp, Qp);
    gemm_out_b_kernel<<<gout, blk, 0, stream>>>(Qp, Wb + 3 * ((size_t)1 << 20),
                                                bo, outf);
  } else if (ws_size >= (size_t)16 << 20) {
    bf16* Wb = wsb;          // 4 Mi el = 8 MiB: Wq|Wk|Wv|Wo bf16
    bf16* Qp = wsb + MD;     // ws [8, 16 MiB); becomes Ctx in place

    wconv_kernel<<<4096, blk, 0, stream>>>(Wq, Wk, Wv, Wo, Wb);
    gemm_qkv_b_kernel<<<gqkv, blk, 0, stream>>>(q, k, v, Wb, Qp, Kp, Vp);
    attn_kernel<<<gattn, blk, 0, stream>>>(Qp, Kp, Vp, Qp);
    gemm_out_b_kernel<<<gout, blk, 0, stream>>>(Qp, Wb + 3 * ((size_t)1 << 20),
                                                bo, outf);
  } else {
    bf16* Qp = wsb;          // ws [0, 8 MiB); becomes Ctx in place

    gemm_qkv_kernel<<<gqkv, blk, 0, stream>>>(q, k, v, Wq, Wk, Wv,
                                              Qp, Kp, Vp);
    attn_kernel<<<gattn, blk, 0, stream>>>(Qp, Kp, Vp, Qp);
    gemm_out_kernel<<<gout, blk, 0, stream>>>(Qp, Wo, bo, outf);
  }
}

// Round 16
// 206.573 us; speedup vs baseline: 1.0155x; 1.0155x over previous
//
#include <hip/hip_runtime.h>
#include <hip/hip_bf16.h>

#define B_  2
#define S_  2048
#define D_  1024
#define H_  16
#define HD_ 64
#define SCALE_ 0.03125f   // 1/sqrt(1024), exact power of two
#define LOG2E_ 1.4426950408889634f
// Q is pre-scaled by SCALE_*LOG2E_ so attention can use exp2 directly.
#define QSCALE_ (SCALE_ * LOG2E_)

typedef __bf16 bf16;
typedef __attribute__((ext_vector_type(8))) __bf16 bf16x8;
typedef __attribute__((ext_vector_type(8))) unsigned short u16x8;
typedef __attribute__((ext_vector_type(4))) unsigned short u16x4v;
typedef __attribute__((ext_vector_type(4))) __bf16 bf16x4;
typedef __attribute__((ext_vector_type(4))) float f32x4;
typedef __attribute__((ext_vector_type(4))) unsigned int u32x4;

__device__ __forceinline__ void gload_lds16(const void* g, void* l) {
  __builtin_amdgcn_global_load_lds(
      (const __attribute__((address_space(1))) unsigned int*)g,
      (__attribute__((address_space(3))) unsigned int*)l,
      16, 0, 0);
}

__device__ __forceinline__ bf16x8 load8(const float* p) {
  const float4 a = *(const float4*)p;
  const float4 b = *(const float4*)(p + 4);
  bf16x8 r;
  r[0] = (bf16)a.x; r[1] = (bf16)a.y; r[2] = (bf16)a.z; r[3] = (bf16)a.w;
  r[4] = (bf16)b.x; r[5] = (bf16)b.y; r[6] = (bf16)b.z; r[7] = (bf16)b.w;
  return r;
}
__device__ __forceinline__ bf16x8 load8(const bf16* p) {
  return *(const bf16x8*)p;
}

// ---------------------------------------------------------------------------
// Weight conversion: Wq|Wk|Wv|Wo fp32 -> one contiguous bf16 buffer (4 Mi el).
// (mid tier only)
// ---------------------------------------------------------------------------
__global__ __launch_bounds__(256)
void wconv_kernel(const float* __restrict__ Wq, const float* __restrict__ Wk,
                  const float* __restrict__ Wv, const float* __restrict__ Wo,
                  bf16* __restrict__ dst)
{
  const int n4  = (blockIdx.x * 256 + threadIdx.x) * 4;
  const int m   = n4 >> 20;
  const int off = n4 & ((1 << 20) - 1);
  const float* src = m == 0 ? Wq : (m == 1 ? Wk : (m == 2 ? Wv : Wo));
  const float4 a = *(const float4*)(src + off);
  bf16x4 o = {(bf16)a.x, (bf16)a.y, (bf16)a.z, (bf16)a.w};
  *(bf16x4*)(dst + n4) = o;
}

// ---------------------------------------------------------------------------
// TOP-TIER conversion: weights (4 Mi el) + q/k/v activations (12 Mi el) ->
// bf16. dst layout (elements): [0,4Mi)=Wq|Wk|Wv|Wo, [4Mi,8Mi)=Qp (skipped),
// [8,12)=q, [12,16)=k, [16,20)=v. grid 16384 x 256, 4 el/thread.
// ---------------------------------------------------------------------------
__global__ __launch_bounds__(256)
void conv_kernel(const float* __restrict__ Wq, const float* __restrict__ Wk,
                 const float* __restrict__ Wv, const float* __restrict__ Wo,
                 const float* __restrict__ q, const float* __restrict__ k,
                 const float* __restrict__ v, bf16* __restrict__ dst)
{
  const size_t MI = (size_t)1 << 20;
  const size_t n4 = ((size_t)blockIdx.x * 256 + threadIdx.x) * 4;
  const float* src;
  size_t so, dof;
  if (n4 < 4 * MI) {                       // weights
    const int m = (int)(n4 >> 20);
    src = m == 0 ? Wq : (m == 1 ? Wk : (m == 2 ? Wv : Wo));
    so  = n4 & (MI - 1);
    dof = n4;
  } else {                                  // activations
    const size_t a = n4 - 4 * MI;           // [0, 12Mi)
    const int m = (int)(a >> 22);           // 4 Mi el per activation
    src = m == 0 ? q : (m == 1 ? k : v);
    so  = a & (4 * MI - 1);
    dof = n4 + 4 * MI;                      // skip the Qp region
  }
  const float4 a4 = *(const float4*)(src + so);
  bf16x4 o = {(bf16)a4.x, (bf16)a4.y, (bf16)a4.z, (bf16)a4.w};
  *(bf16x4*)(dst + dof) = o;
}

// ---------------------------------------------------------------------------
// TOP-TIER QKV projection (round-5 exact, best measured): pure-m97 128x128,
// BOTH operands bf16 via global_load_lds. grid (32, 24).
// ---------------------------------------------------------------------------
__global__ __launch_bounds__(256, 2)
void gemm_qkv3_kernel(const bf16* __restrict__ Ab, const bf16* __restrict__ Wb,
                      bf16* __restrict__ Cq, bf16* __restrict__ Ck,
                      bf16* __restrict__ Cv)
{
  __shared__ bf16 lA[128 * 32];
  __shared__ bf16 lB[128 * 32];

  const int sel = blockIdx.y >> 3;
  const int bn  = blockIdx.y & 7;
  const bf16* A  = Ab + ((size_t)sel << 22);
  const bf16* Bw = Wb + ((size_t)sel << 20);
  bf16*       C  = sel == 0 ? Cq : (sel == 1 ? Ck : Cv);
  const float scale = sel == 0 ? QSCALE_ : 1.0f;

  const int t    = threadIdx.x;
  const int wave = t >> 6;
  const int lane = t & 63;
  const int quad = lane >> 4;
  const int l16  = lane & 15;
  const int bm = blockIdx.x;
  const int wm = (wave >> 1) * 64;
  const int wn = (wave & 1) * 64;

  const int srow = t >> 2;
  const int scol = (t & 3) * 8;
  const bf16* gA = A  + (size_t)(bm * 128 + srow) * D_ + scol;
  const bf16* gB = Bw + (size_t)(bn * 128 + srow) * D_ + scol;

  f32x4 acc[4][4] = {};

  for (int k0 = 0; k0 < D_; k0 += 32) {
    __syncthreads();
    gload_lds16(gA,                   (char*)lA + wave * 1024);
    gload_lds16(gA + (size_t)64 * D_, (char*)lA + 4096 + wave * 1024);
    gload_lds16(gB,                   (char*)lB + wave * 1024);
    gload_lds16(gB + (size_t)64 * D_, (char*)lB + 4096 + wave * 1024);
    __syncthreads();

    bf16x8 af[4], bfr[4];
#pragma unroll
    for (int i = 0; i < 4; ++i) {
      af[i]  = *(const bf16x8*)(lA + (wm + i * 16 + l16) * 32 + quad * 8);
      bfr[i] = *(const bf16x8*)(lB + (wn + i * 16 + l16) * 32 + quad * 8);
    }
#pragma unroll
    for (int mi = 0; mi < 4; ++mi)
#pragma unroll
      for (int ni = 0; ni < 4; ++ni)
        acc[mi][ni] = __builtin_amdgcn_mfma_f32_16x16x32_bf16(
            af[mi], bfr[ni], acc[mi][ni], 0, 0, 0);

    gA += 32;
    gB += 32;
  }

#pragma unroll
  for (int mi = 0; mi < 4; ++mi) {
#pragma unroll
    for (int ni = 0; ni < 4; ++ni) {
      const int col = bn * 128 + wn + ni * 16 + l16;
#pragma unroll
      for (int r = 0; r < 4; ++r) {
        const int row = bm * 128 + wm + mi * 16 + quad * 4 + r;
        C[(size_t)row * D_ + col] = (bf16)(acc[mi][ni][r] * scale);
      }
    }
  }
}

// ---------------------------------------------------------------------------
// MID-TIER QKV projection: A fp32 (reg-staged + cvt) with cross-iteration
// register prefetch, W bf16 via global_load_lds. grid (32, 24).
// ---------------------------------------------------------------------------
__global__ __launch_bounds__(256, 2)
void gemm_qkv_b_kernel(const float* __restrict__ Aq, const float* __restrict__ Ak,
                       const float* __restrict__ Av, const bf16* __restrict__ Wb,
                       bf16* __restrict__ Cq, bf16* __restrict__ Ck,
                       bf16* __restrict__ Cv)
{
  __shared__ bf16 lA[128 * 32];
  __shared__ bf16 lB[128 * 32];

  const int sel = blockIdx.y >> 3;
  const int bn  = blockIdx.y & 7;
  const float* A  = sel == 0 ? Aq : (sel == 1 ? Ak : Av);
  const bf16*  Bw = Wb + ((size_t)sel << 20);
  bf16*        C  = sel == 0 ? Cq : (sel == 1 ? Ck : Cv);
  const float scale = sel == 0 ? QSCALE_ : 1.0f;

  const int t    = threadIdx.x;
  const int wave = t >> 6;
  const int lane = t & 63;
  const int quad = lane >> 4;
  const int l16  = lane & 15;
  const int bm = blockIdx.x;
  const int wm = (wave >> 1) * 64;
  const int wn = (wave & 1) * 64;

  const int srow = t >> 2;
  const int scol = (t & 3) * 8;
  const float* gA  = A  + (size_t)(bm * 128 + srow) * D_ + scol;
  const bf16*  gBb = Bw + (size_t)(bn * 128 + srow) * D_ + scol;

  f32x4 acc[4][4] = {};

  bf16x8 a0 = load8(gA);
  bf16x8 a1 = load8(gA + (size_t)64 * D_);

  for (int k0 = 0; k0 < D_; k0 += 32) {
    __syncthreads();
    *(bf16x8*)(lA + srow * 32 + scol)        = a0;
    *(bf16x8*)(lA + (srow + 64) * 32 + scol) = a1;
    gload_lds16(gBb,                   (char*)lB + wave * 1024);
    gload_lds16(gBb + (size_t)64 * D_, (char*)lB + 4096 + wave * 1024);
    gBb += 32;
    __syncthreads();

    if (k0 + 32 < D_) {     // prefetch next A tile during the MFMA phase
      gA += 32;
      a0 = load8(gA);
      a1 = load8(gA + (size_t)64 * D_);
    }

    bf16x8 af[4], bfr[4];
#pragma unroll
    for (int i = 0; i < 4; ++i) {
      af[i]  = *(const bf16x8*)(lA + (wm + i * 16 + l16) * 32 + quad * 8);
      bfr[i] = *(const bf16x8*)(lB + (wn + i * 16 + l16) * 32 + quad * 8);
    }
#pragma unroll
    for (int mi = 0; mi < 4; ++mi)
#pragma unroll
      for (int ni = 0; ni < 4; ++ni)
        acc[mi][ni] = __builtin_amdgcn_mfma_f32_16x16x32_bf16(
            af[mi], bfr[ni], acc[mi][ni], 0, 0, 0);
  }

#pragma unroll
  for (int mi = 0; mi < 4; ++mi) {
#pragma unroll
    for (int ni = 0; ni < 4; ++ni) {
      const int col = bn * 128 + wn + ni * 16 + l16;
#pragma unroll
      for (int r = 0; r < 4; ++r) {
        const int row = bm * 128 + wm + mi * 16 + quad * 4 + r;
        C[(size_t)row * D_ + col] = (bf16)(acc[mi][ni][r] * scale);
      }
    }
  }
}

// ---------------------------------------------------------------------------
// FAST output projection (round-5 exact): ctx bf16 + Wo bf16 via
// global_load_lds, fp32 output + bias. Tile 128x64, grid (32, 16).
// ---------------------------------------------------------------------------
__global__ __launch_bounds__(256, 2)
void gemm_out_b_kernel(const bf16* __restrict__ A, const bf16* __restrict__ Bw,
                       const float* __restrict__ bias, float* __restrict__ C)
{
  __shared__ bf16 lA[128 * 32];
  __shared__ bf16 lB[64 * 32];

  const int t    = threadIdx.x;
  const int wave = t >> 6;
  const int lane = t & 63;
  const int quad = lane >> 4;
  const int l16  = lane & 15;
  const int bm = blockIdx.x;
  const int bn = blockIdx.y;
  const int wm = wave * 32;

  const int srow = t >> 2;
  const int scol = (t & 3) * 8;
  const bf16* gA = A  + (size_t)(bm * 128 + srow) * D_ + scol;
  const bf16* gB = Bw + (size_t)(bn * 64 + srow) * D_ + scol;

  f32x4 acc[2][4] = {};

  for (int k0 = 0; k0 < D_; k0 += 32) {
    __syncthreads();
    gload_lds16(gA,                   (char*)lA + wave * 1024);
    gload_lds16(gA + (size_t)64 * D_, (char*)lA + 4096 + wave * 1024);
    gload_lds16(gB,                   (char*)lB + wave * 1024);
    __syncthreads();

    bf16x8 af[2], bfr[4];
#pragma unroll
    for (int i = 0; i < 2; ++i)
      af[i]  = *(const bf16x8*)(lA + (wm + i * 16 + l16) * 32 + quad * 8);
#pragma unroll
    for (int i = 0; i < 4; ++i)
      bfr[i] = *(const bf16x8*)(lB + (i * 16 + l16) * 32 + quad * 8);
#pragma unroll
    for (int mi = 0; mi < 2; ++mi)
#pragma unroll
      for (int ni = 0; ni < 4; ++ni)
        acc[mi][ni] = __builtin_amdgcn_mfma_f32_16x16x32_bf16(
            af[mi], bfr[ni], acc[mi][ni], 0, 0, 0);

    gA += 32;
    gB += 32;
  }

  float bv[4];
#pragma unroll
  for (int ni = 0; ni < 4; ++ni)
    bv[ni] = bias[bn * 64 + ni * 16 + l16];
#pragma unroll
  for (int mi = 0; mi < 2; ++mi) {
#pragma unroll
    for (int ni = 0; ni < 4; ++ni) {
      const int col = bn * 64 + ni * 16 + l16;
#pragma unroll
      for (int r = 0; r < 4; ++r) {
        const int row = bm * 128 + wm + mi * 16 + quad * 4 + r;
        C[(size_t)row * D_ + col] = acc[mi][ni][r] + bv[ni];
      }
    }
  }
}

// ---------------------------------------------------------------------------
// FALLBACK QKV projection (ws < 16 MiB): fp32 weights, QSCALE_ fold on Q.
// ---------------------------------------------------------------------------
__global__ __launch_bounds__(256, 2)
void gemm_qkv_kernel(const float* __restrict__ Aq, const float* __restrict__ Ak,
                     const float* __restrict__ Av, const float* __restrict__ Wq,
                     const float* __restrict__ Wk, const float* __restrict__ Wv,
                     bf16* __restrict__ Cq, bf16* __restrict__ Ck,
                     bf16* __restrict__ Cv)
{
  __shared__ bf16 lA[128 * 32];
  __shared__ bf16 lB[128 * 32];

  const int sel = blockIdx.y >> 3;
  const int bn  = blockIdx.y & 7;
  const float* A  = sel == 0 ? Aq : (sel == 1 ? Ak : Av);
  const float* Bw = sel == 0 ? Wq : (sel == 1 ? Wk : Wv);
  bf16*        C  = sel == 0 ? Cq : (sel == 1 ? Ck : Cv);
  const float scale = sel == 0 ? QSCALE_ : 1.0f;

  const int t    = threadIdx.x;
  const int wave = t >> 6;
  const int lane = t & 63;
  const int quad = lane >> 4;
  const int l16  = lane & 15;
  const int bm = blockIdx.x;
  const int wm = (wave >> 1) * 64;
  const int wn = (wave & 1) * 64;

  const int srow = t >> 2;
  const int scol = (t & 3) * 8;
  const float* gA = A  + (size_t)(bm * 128 + srow) * D_ + scol;
  const float* gB = Bw + (size_t)(bn * 128 + srow) * D_ + scol;

  f32x4 acc[4][4] = {};

  for (int k0 = 0; k0 < D_; k0 += 32) {
    const bf16x8 a0 = load8(gA);
    const bf16x8 a1 = load8(gA + (size_t)64 * D_);
    const bf16x8 b0 = load8(gB);
    const bf16x8 b1 = load8(gB + (size_t)64 * D_);

    __syncthreads();
    *(bf16x8*)(lA + srow * 32 + scol)        = a0;
    *(bf16x8*)(lA + (srow + 64) * 32 + scol) = a1;
    *(bf16x8*)(lB + srow * 32 + scol)        = b0;
    *(bf16x8*)(lB + (srow + 64) * 32 + scol) = b1;
    __syncthreads();

    bf16x8 af[4], bfr[4];
#pragma unroll
    for (int i = 0; i < 4; ++i) {
      af[i]  = *(const bf16x8*)(lA + (wm + i * 16 + l16) * 32 + quad * 8);
      bfr[i] = *(const bf16x8*)(lB + (wn + i * 16 + l16) * 32 + quad * 8);
    }
#pragma unroll
    for (int mi = 0; mi < 4; ++mi)
#pragma unroll
      for (int ni = 0; ni < 4; ++ni)
        acc[mi][ni] = __builtin_amdgcn_mfma_f32_16x16x32_bf16(
            af[mi], bfr[ni], acc[mi][ni], 0, 0, 0);

    gA += 32;
    gB += 32;
  }

#pragma unroll
  for (int mi = 0; mi < 4; ++mi) {
#pragma unroll
    for (int ni = 0; ni < 4; ++ni) {
      const int col = bn * 128 + wn + ni * 16 + l16;
#pragma unroll
      for (int r = 0; r < 4; ++r) {
        const int row = bm * 128 + wm + mi * 16 + quad * 4 + r;
        C[(size_t)row * D_ + col] = (bf16)(acc[mi][ni][r] * scale);
      }
    }
  }
}

// ---------------------------------------------------------------------------
// FALLBACK output projection (ws < 16 MiB): fp32 weights. Tile 128x64.
// ---------------------------------------------------------------------------
__global__ __launch_bounds__(256, 2)
void gemm_out_kernel(const bf16* __restrict__ A, const float* __restrict__ Bw,
                     const float* __restrict__ bias, float* __restrict__ C)
{
  __shared__ bf16 lA[128 * 32];
  __shared__ bf16 lB[64 * 32];

  const int t    = threadIdx.x;
  const int wave = t >> 6;
  const int lane = t & 63;
  const int quad = lane >> 4;
  const int l16  = lane & 15;
  const int bm = blockIdx.x;
  const int bn = blockIdx.y;
  const int wm = wave * 32;

  const int srow = t >> 2;
  const int scol = (t & 3) * 8;
  const bf16*  gA = A  + (size_t)(bm * 128 + srow) * D_ + scol;
  const float* gB = Bw + (size_t)(bn * 64 + srow) * D_ + scol;

  f32x4 acc[2][4] = {};

  for (int k0 = 0; k0 < D_; k0 += 32) {
    const bf16x8 a0 = load8(gA);
    const bf16x8 a1 = load8(gA + (size_t)64 * D_);
    const bf16x8 b0 = load8(gB);

    __syncthreads();
    *(bf16x8*)(lA + srow * 32 + scol)        = a0;
    *(bf16x8*)(lA + (srow + 64) * 32 + scol) = a1;
    *(bf16x8*)(lB + srow * 32 + scol)        = b0;
    __syncthreads();

    bf16x8 af[2], bfr[4];
#pragma unroll
    for (int i = 0; i < 2; ++i)
      af[i]  = *(const bf16x8*)(lA + (wm + i * 16 + l16) * 32 + quad * 8);
#pragma unroll
    for (int i = 0; i < 4; ++i)
      bfr[i] = *(const bf16x8*)(lB + (i * 16 + l16) * 32 + quad * 8);
#pragma unroll
    for (int mi = 0; mi < 2; ++mi)
#pragma unroll
      for (int ni = 0; ni < 4; ++ni)
        acc[mi][ni] = __builtin_amdgcn_mfma_f32_16x16x32_bf16(
            af[mi], bfr[ni], acc[mi][ni], 0, 0, 0);

    gA += 32;
    gB += 32;
  }

  float bv[4];
#pragma unroll
  for (int ni = 0; ni < 4; ++ni)
    bv[ni] = bias[bn * 64 + ni * 16 + l16];
#pragma unroll
  for (int mi = 0; mi < 2; ++mi) {
#pragma unroll
    for (int ni = 0; ni < 4; ++ni) {
      const int col = bn * 64 + ni * 16 + l16;
#pragma unroll
      for (int r = 0; r < 4; ++r) {
        const int row = bm * 128 + wm + mi * 16 + quad * 4 + r;
        C[(size_t)row * D_ + col] = acc[mi][ni][r] + bv[ni];
      }
    }
  }
}

// ---------------------------------------------------------------------------
// Flash attention v9 = v8 per-wave code with 256 Q-ROWS PER BLOCK (8 waves,
// 512 threads). Same 8 waves/CU as v8 (1x8 vs 2x4), but each staged K/V tile
// now serves 256 q-rows instead of 128: K/V L2 traffic and LDS staging per
// q-row HALVE. Risk (accepted): loses v8's 2-independent-blocks phase
// overlap; if that dominates, revert to v8 next round (best is locked in).
//  - In-register P via cvt_pk + permlane butterfly (unchanged).
//  - SWAPPED QK^T; per-lane denominator; reg prefetch of next K/V tile.
//  - Staging for 512 threads: Q 4x(row t>>3 + 64i); K one b128/thread
//    (64x64 exact); V dp=t&31, kg=t>>5 in [0,16): 4 keys x 1 dword/thread,
//    8-byte lVT stores.
// grid (8, 32) = 256 blocks = 1/CU; LDS 54 KiB.
// ---------------------------------------------------------------------------
__global__ __launch_bounds__(512, 1)
void attn_kernel(const bf16* Q, const bf16* __restrict__ K,
                 const bf16* __restrict__ V, bf16* O)
{
  __shared__ bf16 lQ[256 * 72];
  __shared__ bf16 lK[64 * 72];
  __shared__ bf16 lVT[64 * 72];

  const int t    = threadIdx.x;
  const int wave = t >> 6;          // 0..7
  const int lane = t & 63;
  const int quad = lane >> 4;
  const int l16  = lane & 15;

  // XCD swizzle: 256 blocks; flat bits [2:0]=xcd, [5:3]=qt, [7:6]=head-in-xcd
  const int flat = blockIdx.y * 8 + blockIdx.x;
  const int qt   = (flat >> 3) & 7;
  const int bh   = (flat & 7) * 4 + (flat >> 6);
  const size_t headoff =
      (size_t)(bh >> 4) * ((size_t)S_ * D_) + (size_t)(bh & 15) * HD_;

  const bf16* Kb = K + headoff;
  const bf16* Vb = V + headoff;

  // ---- stage Q tile (256 rows)
  const int sr  = t >> 3;          // 0..63
  const int scx = (t & 7) * 8;
#pragma unroll
  for (int i = 0; i < 4; ++i) {
    const bf16x8 qv =
        *(const bf16x8*)(Q + headoff + (size_t)(qt * 256 + sr + 64 * i) * D_ + scx);
    *(bf16x8*)(lQ + (sr + 64 * i) * 72 + scx) = qv;
  }
  __syncthreads();

  // Q fragments (B-operand of swapped QK^T): lane's l16 picks the q-row.
  bf16x8 qf[2][2];
#pragma unroll
  for (int m = 0; m < 2; ++m)
#pragma unroll
    for (int ks = 0; ks < 2; ++ks)
      qf[m][ks] = *(const bf16x8*)(lQ + (wave * 32 + m * 16 + l16) * 72 +
                                   (ks * 4 + quad) * 8);

  f32x4 acco[2][4] = {};
  float den[2] = {0.f, 0.f};

  const int dp = t & 31;    // d-pair index: columns 2dp, 2dp+1
  const int kg = t >> 5;    // key group 0..15: keys kg*4 .. kg*4+3

  // ---- prefetch registers
  bf16x8 pk0;
  unsigned int pv[4];
  {
    const bf16* kb = Kb + (size_t)sr * D_ + scx;        // kt = 0, 64x64 exact
    pk0 = load8(kb);
    const bf16* vb = Vb + (size_t)(kg * 4) * D_ + 2 * dp;
#pragma unroll
    for (int j = 0; j < 4; ++j)
      pv[j] = *(const unsigned int*)(vb + (size_t)j * D_);
  }

  for (int kt = 0; kt < S_ / 64; ++kt) {
    __syncthreads();   // prev iteration's lK/lVT reads done

    // ---- commit prefetched K tile (one b128 per thread)
    *(bf16x8*)(lK + sr * 72 + scx) = pk0;
    // ---- commit prefetched V (transposed): rows 2dp, 2dp+1, keys kg*4..+3
    {
      u16x4v w0, w1;
#pragma unroll
      for (int j = 0; j < 4; ++j) {
        w0[j] = (unsigned short)(pv[j] & 0xffffu);
        w1[j] = (unsigned short)(pv[j] >> 16);
      }
      *(u16x4v*)(lVT + (2 * dp) * 72 + kg * 4)     = w0;
      *(u16x4v*)(lVT + (2 * dp + 1) * 72 + kg * 4) = w1;
    }
    __syncthreads();   // staging visible

    // ---- prefetch next iteration (in flight during compute)
    if (kt + 1 < S_ / 64) {
      const bf16* kb = Kb + (size_t)((kt + 1) * 64 + sr) * D_ + scx;
      pk0 = load8(kb);
      const bf16* vb = Vb + (size_t)((kt + 1) * 64 + kg * 4) * D_ + 2 * dp;
#pragma unroll
      for (int j = 0; j < 4; ++j)
        pv[j] = *(const unsigned int*)(vb + (size_t)j * D_);
    }

    // ---- S^T = K Q^T  (Q pre-scaled; kf reused across both m-halves)
    f32x4 sc[2][4] = {};
#pragma unroll
    for (int nt = 0; nt < 4; ++nt) {
#pragma unroll
      for (int ks = 0; ks < 2; ++ks) {
        const bf16x8 kf =
            *(const bf16x8*)(lK + (nt * 16 + l16) * 72 + (ks * 4 + quad) * 8);
#pragma unroll
        for (int m = 0; m < 2; ++m)
          sc[m][nt] = __builtin_amdgcn_mfma_f32_16x16x32_bf16(
              kf, qf[m][ks], sc[m][nt], 0, 0, 0);
      }
    }

    // ---- p = exp2(s); pack to bf16 words; permlane butterfly -> pf in regs
    bf16x8 pf[2][2];
#pragma unroll
    for (int m = 0; m < 2; ++m) {
      unsigned int W[4][2];      // [nt][j], fully static indexing
#pragma unroll
      for (int nt = 0; nt < 4; ++nt) {
        const float p0 = __builtin_amdgcn_exp2f(sc[m][nt][0]);
        const float p1 = __builtin_amdgcn_exp2f(sc[m][nt][1]);
        const float p2 = __builtin_amdgcn_exp2f(sc[m][nt][2]);
        const float p3 = __builtin_amdgcn_exp2f(sc[m][nt][3]);
        den[m] += (p0 + p1) + (p2 + p3);
        asm("v_cvt_pk_bf16_f32 %0, %1, %2" : "=v"(W[nt][0]) : "v"(p0), "v"(p1));
        asm("v_cvt_pk_bf16_f32 %0, %1, %2" : "=v"(W[nt][1]) : "v"(p2), "v"(p3));
      }
#pragma unroll
      for (int ks = 0; ks < 2; ++ks) {
        unsigned int r0 = W[2 * ks][0], s0 = W[2 * ks + 1][0];
        unsigned int r1 = W[2 * ks][1], s1 = W[2 * ks + 1][1];
        asm("v_permlane32_swap_b32 %0, %1" : "+v"(r0), "+v"(s0));
        asm("v_permlane16_swap_b32 %0, %1" : "+v"(r0), "+v"(s0));
        asm("v_permlane32_swap_b32 %0, %1" : "+v"(r1), "+v"(s1));
        asm("v_permlane16_swap_b32 %0, %1" : "+v"(r1), "+v"(s1));
        const u32x4 pw = {r0, r1, s0, s1};   // words w0,w1,w2,w3
        pf[m][ks] = __builtin_bit_cast(bf16x8, pw);
      }
    }

    // ---- O += P V  (vf reused across both m-halves; pf from registers)
#pragma unroll
    for (int dt = 0; dt < 4; ++dt) {
#pragma unroll
      for (int ks = 0; ks < 2; ++ks) {
        const bf16x8 vf =
            *(const bf16x8*)(lVT + (dt * 16 + l16) * 72 + (ks * 4 + quad) * 8);
#pragma unroll
        for (int m = 0; m < 2; ++m)
          acco[m][dt] = __builtin_amdgcn_mfma_f32_16x16x32_bf16(
              pf[m][ks], vf, acco[m][dt], 0, 0, 0);
      }
    }
  }

  // ---- epilogue: finish denominator (sum the 4 key-quads), normalize, store
#pragma unroll
  for (int m = 0; m < 2; ++m) {
    den[m] += __shfl_xor(den[m], 16);
    den[m] += __shfl_xor(den[m], 32);
  }
#pragma unroll
  for (int m = 0; m < 2; ++m) {
#pragma unroll
    for (int r = 0; r < 4; ++r) {
      const float rd  = 1.f / __shfl(den[m], quad * 4 + r);
      const int   row = qt * 256 + wave * 32 + m * 16 + quad * 4 + r;
#pragma unroll
      for (int dt = 0; dt < 4; ++dt)
        O[headoff + (size_t)row * D_ + dt * 16 + l16] =
            (bf16)(acco[m][dt][r] * rd);
    }
  }
}

// ---------------------------------------------------------------------------
// Tiers:
//  ws >= 40 MiB: conv (W + q/k/v -> bf16), pure-bf16 QKV GEMM (128x128),
//                attn v9 (256-row blocks, in-register P), out (128x64).
//                ws: Wb[0,8MiB) Qp[8,16) Aq[16,24) Ak[24,32) Av[32,40).
//  ws >= 16 MiB: wconv + fp32-A reg-prefetch QKV, attn, out.
//  else:         fp32-weight fallback.
// K'/V' live in d_out (bf16 view); final GEMM overwrites d_out with fp32.
// ---------------------------------------------------------------------------
extern "C" void kernel_launch(void* const* d_in, const int* in_sizes, int n_in,
                              void* d_out, int out_size, void* d_ws, size_t ws_size,
                              hipStream_t stream)
{
  const float* q  = (const float*)d_in[0];
  const float* k  = (const float*)d_in[1];
  const float* v  = (const float*)d_in[2];
  const float* Wq = (const float*)d_in[3];
  const float* Wk = (const float*)d_in[4];
  const float* Wv = (const float*)d_in[5];
  const float* Wo = (const float*)d_in[6];
  const float* bo = (const float*)d_in[7];
  float* outf = (float*)d_out;
  bf16*  outs = (bf16*)d_out;
  bf16*  wsb  = (bf16*)d_ws;

  const size_t MD = (size_t)B_ * S_ * D_;   // 4 Mi elements

  dim3 blk(256);
  dim3 blka(512);
  dim3 gqkv(B_ * S_ / 128, 24);
  dim3 gattn(S_ / 256, B_ * H_);
  dim3 gout(B_ * S_ / 128, D_ / 64);

  bf16* Kp = outs;          // d_out [0, 8Mi)
  bf16* Vp = outs + MD;     // d_out [8Mi, 16Mi)

  if (ws_size >= (size_t)40 << 20) {
    bf16* Wb = wsb;            // [0, 4Mi el): Wq|Wk|Wv|Wo bf16
    bf16* Qp = wsb + MD;       // [4Mi, 8Mi el): Q' -> ctx in place
    bf16* Ab = wsb + 2 * MD;   // [8Mi, 20Mi el): q|k|v bf16

    conv_kernel<<<16384, blk, 0, stream>>>(Wq, Wk, Wv, Wo, q, k, v, wsb);
    gemm_qkv3_kernel<<<gqkv, blk, 0, stream>>>(Ab, Wb, Qp, Kp, Vp);
    attn_kernel<<<gattn, blka, 0, stream>>>(Qp, Kp, Vp, Qp);
    gemm_out_b_kernel<<<gout, blk, 0, stream>>>(Qp, Wb + 3 * ((size_t)1 << 20),
                                                bo, outf);
  } else if (ws_size >= (size_t)16 << 20) {
    bf16* Wb = wsb;          // 4 Mi el = 8 MiB: Wq|Wk|Wv|Wo bf16
    bf16* Qp = wsb + MD;     // ws [8, 16 MiB); becomes Ctx in place

    wconv_kernel<<<4096, blk, 0, stream>>>(Wq, Wk, Wv, Wo, Wb);
    gemm_qkv_b_kernel<<<gqkv, blk, 0, stream>>>(q, k, v, Wb, Qp, Kp, Vp);
    attn_kernel<<<gattn, blka, 0, stream>>>(Qp, Kp, Vp, Qp);
    gemm_out_b_kernel<<<gout, blk, 0, stream>>>(Qp, Wb + 3 * ((size_t)1 << 20),
                                                bo, outf);
  } else {
    bf16* Qp = wsb;          // ws [0, 8 MiB); becomes Ctx in place

    gemm_qkv_kernel<<<gqkv, blk, 0, stream>>>(q, k, v, Wq, Wk, Wv,
                                              Qp, Kp, Vp);
    attn_kernel<<<gattn, blka, 0, stream>>>(Qp, Kp, Vp, Qp);
    gemm_out_kernel<<<gout, blk, 0, stream>>>(Qp, Wo, bo, outf);
  }
}

// Round 17
// 203.039 us; speedup vs baseline: 1.0332x; 1.0174x over previous
//
#include <hip/hip_runtime.h>
#include <hip/hip_bf16.h>

#define B_  2
#define S_  2048
#define D_  1024
#define H_  16
#define HD_ 64
#define SCALE_ 0.03125f   // 1/sqrt(1024), exact power of two
#define LOG2E_ 1.4426950408889634f
// Q is pre-scaled by SCALE_*LOG2E_ so attention can use exp2 directly.
#define QSCALE_ (SCALE_ * LOG2E_)

typedef __bf16 bf16;
typedef __attribute__((ext_vector_type(8))) __bf16 bf16x8;
typedef __attribute__((ext_vector_type(8))) unsigned short u16x8;
typedef __attribute__((ext_vector_type(4))) unsigned short u16x4v;
typedef __attribute__((ext_vector_type(4))) __bf16 bf16x4;
typedef __attribute__((ext_vector_type(4))) float f32x4;
typedef __attribute__((ext_vector_type(4))) unsigned int u32x4;

__device__ __forceinline__ void gload_lds16(const void* g, void* l) {
  __builtin_amdgcn_global_load_lds(
      (const __attribute__((address_space(1))) unsigned int*)g,
      (__attribute__((address_space(3))) unsigned int*)l,
      16, 0, 0);
}

__device__ __forceinline__ bf16x8 load8(const float* p) {
  const float4 a = *(const float4*)p;
  const float4 b = *(const float4*)(p + 4);
  bf16x8 r;
  r[0] = (bf16)a.x; r[1] = (bf16)a.y; r[2] = (bf16)a.z; r[3] = (bf16)a.w;
  r[4] = (bf16)b.x; r[5] = (bf16)b.y; r[6] = (bf16)b.z; r[7] = (bf16)b.w;
  return r;
}
__device__ __forceinline__ bf16x8 load8(const bf16* p) {
  return *(const bf16x8*)p;
}

// ---------------------------------------------------------------------------
// Weight conversion: Wq|Wk|Wv|Wo fp32 -> one contiguous bf16 buffer (4 Mi el).
// (mid tier only)
// ---------------------------------------------------------------------------
__global__ __launch_bounds__(256)
void wconv_kernel(const float* __restrict__ Wq, const float* __restrict__ Wk,
                  const float* __restrict__ Wv, const float* __restrict__ Wo,
                  bf16* __restrict__ dst)
{
  const int n4  = (blockIdx.x * 256 + threadIdx.x) * 4;
  const int m   = n4 >> 20;
  const int off = n4 & ((1 << 20) - 1);
  const float* src = m == 0 ? Wq : (m == 1 ? Wk : (m == 2 ? Wv : Wo));
  const float4 a = *(const float4*)(src + off);
  bf16x4 o = {(bf16)a.x, (bf16)a.y, (bf16)a.z, (bf16)a.w};
  *(bf16x4*)(dst + n4) = o;
}

// ---------------------------------------------------------------------------
// TOP-TIER conversion: weights (4 Mi el) + q/k/v activations (12 Mi el) ->
// bf16. dst layout (elements): [0,4Mi)=Wq|Wk|Wv|Wo, [4Mi,8Mi)=Qp (skipped),
// [8,12)=q, [12,16)=k, [16,20)=v. grid 16384 x 256, 4 el/thread.
// ---------------------------------------------------------------------------
__global__ __launch_bounds__(256)
void conv_kernel(const float* __restrict__ Wq, const float* __restrict__ Wk,
                 const float* __restrict__ Wv, const float* __restrict__ Wo,
                 const float* __restrict__ q, const float* __restrict__ k,
                 const float* __restrict__ v, bf16* __restrict__ dst)
{
  const size_t MI = (size_t)1 << 20;
  const size_t n4 = ((size_t)blockIdx.x * 256 + threadIdx.x) * 4;
  const float* src;
  size_t so, dof;
  if (n4 < 4 * MI) {                       // weights
    const int m = (int)(n4 >> 20);
    src = m == 0 ? Wq : (m == 1 ? Wk : (m == 2 ? Wv : Wo));
    so  = n4 & (MI - 1);
    dof = n4;
  } else {                                  // activations
    const size_t a = n4 - 4 * MI;           // [0, 12Mi)
    const int m = (int)(a >> 22);           // 4 Mi el per activation
    src = m == 0 ? q : (m == 1 ? k : v);
    so  = a & (4 * MI - 1);
    dof = n4 + 4 * MI;                      // skip the Qp region
  }
  const float4 a4 = *(const float4*)(src + so);
  bf16x4 o = {(bf16)a4.x, (bf16)a4.y, (bf16)a4.z, (bf16)a4.w};
  *(bf16x4*)(dst + dof) = o;
}

// ---------------------------------------------------------------------------
// TOP-TIER QKV projection (round-5 exact, best measured): pure-m97 128x128,
// BOTH operands bf16 via global_load_lds. grid (32, 24).
// ---------------------------------------------------------------------------
__global__ __launch_bounds__(256, 2)
void gemm_qkv3_kernel(const bf16* __restrict__ Ab, const bf16* __restrict__ Wb,
                      bf16* __restrict__ Cq, bf16* __restrict__ Ck,
                      bf16* __restrict__ Cv)
{
  __shared__ bf16 lA[128 * 32];
  __shared__ bf16 lB[128 * 32];

  const int sel = blockIdx.y >> 3;
  const int bn  = blockIdx.y & 7;
  const bf16* A  = Ab + ((size_t)sel << 22);
  const bf16* Bw = Wb + ((size_t)sel << 20);
  bf16*       C  = sel == 0 ? Cq : (sel == 1 ? Ck : Cv);
  const float scale = sel == 0 ? QSCALE_ : 1.0f;

  const int t    = threadIdx.x;
  const int wave = t >> 6;
  const int lane = t & 63;
  const int quad = lane >> 4;
  const int l16  = lane & 15;
  const int bm = blockIdx.x;
  const int wm = (wave >> 1) * 64;
  const int wn = (wave & 1) * 64;

  const int srow = t >> 2;
  const int scol = (t & 3) * 8;
  const bf16* gA = A  + (size_t)(bm * 128 + srow) * D_ + scol;
  const bf16* gB = Bw + (size_t)(bn * 128 + srow) * D_ + scol;

  f32x4 acc[4][4] = {};

  for (int k0 = 0; k0 < D_; k0 += 32) {
    __syncthreads();
    gload_lds16(gA,                   (char*)lA + wave * 1024);
    gload_lds16(gA + (size_t)64 * D_, (char*)lA + 4096 + wave * 1024);
    gload_lds16(gB,                   (char*)lB + wave * 1024);
    gload_lds16(gB + (size_t)64 * D_, (char*)lB + 4096 + wave * 1024);
    __syncthreads();

    bf16x8 af[4], bfr[4];
#pragma unroll
    for (int i = 0; i < 4; ++i) {
      af[i]  = *(const bf16x8*)(lA + (wm + i * 16 + l16) * 32 + quad * 8);
      bfr[i] = *(const bf16x8*)(lB + (wn + i * 16 + l16) * 32 + quad * 8);
    }
#pragma unroll
    for (int mi = 0; mi < 4; ++mi)
#pragma unroll
      for (int ni = 0; ni < 4; ++ni)
        acc[mi][ni] = __builtin_amdgcn_mfma_f32_16x16x32_bf16(
            af[mi], bfr[ni], acc[mi][ni], 0, 0, 0);

    gA += 32;
    gB += 32;
  }

#pragma unroll
  for (int mi = 0; mi < 4; ++mi) {
#pragma unroll
    for (int ni = 0; ni < 4; ++ni) {
      const int col = bn * 128 + wn + ni * 16 + l16;
#pragma unroll
      for (int r = 0; r < 4; ++r) {
        const int row = bm * 128 + wm + mi * 16 + quad * 4 + r;
        C[(size_t)row * D_ + col] = (bf16)(acc[mi][ni][r] * scale);
      }
    }
  }
}

// ---------------------------------------------------------------------------
// MID-TIER QKV projection: A fp32 (reg-staged + cvt) with cross-iteration
// register prefetch, W bf16 via global_load_lds. grid (32, 24).
// ---------------------------------------------------------------------------
__global__ __launch_bounds__(256, 2)
void gemm_qkv_b_kernel(const float* __restrict__ Aq, const float* __restrict__ Ak,
                       const float* __restrict__ Av, const bf16* __restrict__ Wb,
                       bf16* __restrict__ Cq, bf16* __restrict__ Ck,
                       bf16* __restrict__ Cv)
{
  __shared__ bf16 lA[128 * 32];
  __shared__ bf16 lB[128 * 32];

  const int sel = blockIdx.y >> 3;
  const int bn  = blockIdx.y & 7;
  const float* A  = sel == 0 ? Aq : (sel == 1 ? Ak : Av);
  const bf16*  Bw = Wb + ((size_t)sel << 20);
  bf16*        C  = sel == 0 ? Cq : (sel == 1 ? Ck : Cv);
  const float scale = sel == 0 ? QSCALE_ : 1.0f;

  const int t    = threadIdx.x;
  const int wave = t >> 6;
  const int lane = t & 63;
  const int quad = lane >> 4;
  const int l16  = lane & 15;
  const int bm = blockIdx.x;
  const int wm = (wave >> 1) * 64;
  const int wn = (wave & 1) * 64;

  const int srow = t >> 2;
  const int scol = (t & 3) * 8;
  const float* gA  = A  + (size_t)(bm * 128 + srow) * D_ + scol;
  const bf16*  gBb = Bw + (size_t)(bn * 128 + srow) * D_ + scol;

  f32x4 acc[4][4] = {};

  bf16x8 a0 = load8(gA);
  bf16x8 a1 = load8(gA + (size_t)64 * D_);

  for (int k0 = 0; k0 < D_; k0 += 32) {
    __syncthreads();
    *(bf16x8*)(lA + srow * 32 + scol)        = a0;
    *(bf16x8*)(lA + (srow + 64) * 32 + scol) = a1;
    gload_lds16(gBb,                   (char*)lB + wave * 1024);
    gload_lds16(gBb + (size_t)64 * D_, (char*)lB + 4096 + wave * 1024);
    gBb += 32;
    __syncthreads();

    if (k0 + 32 < D_) {     // prefetch next A tile during the MFMA phase
      gA += 32;
      a0 = load8(gA);
      a1 = load8(gA + (size_t)64 * D_);
    }

    bf16x8 af[4], bfr[4];
#pragma unroll
    for (int i = 0; i < 4; ++i) {
      af[i]  = *(const bf16x8*)(lA + (wm + i * 16 + l16) * 32 + quad * 8);
      bfr[i] = *(const bf16x8*)(lB + (wn + i * 16 + l16) * 32 + quad * 8);
    }
#pragma unroll
    for (int mi = 0; mi < 4; ++mi)
#pragma unroll
      for (int ni = 0; ni < 4; ++ni)
        acc[mi][ni] = __builtin_amdgcn_mfma_f32_16x16x32_bf16(
            af[mi], bfr[ni], acc[mi][ni], 0, 0, 0);
  }

#pragma unroll
  for (int mi = 0; mi < 4; ++mi) {
#pragma unroll
    for (int ni = 0; ni < 4; ++ni) {
      const int col = bn * 128 + wn + ni * 16 + l16;
#pragma unroll
      for (int r = 0; r < 4; ++r) {
        const int row = bm * 128 + wm + mi * 16 + quad * 4 + r;
        C[(size_t)row * D_ + col] = (bf16)(acc[mi][ni][r] * scale);
      }
    }
  }
}

// ---------------------------------------------------------------------------
// FAST output projection (round-5 exact): ctx bf16 + Wo bf16 via
// global_load_lds, fp32 output + bias. Tile 128x64, grid (32, 16).
// ---------------------------------------------------------------------------
__global__ __launch_bounds__(256, 2)
void gemm_out_b_kernel(const bf16* __restrict__ A, const bf16* __restrict__ Bw,
                       const float* __restrict__ bias, float* __restrict__ C)
{
  __shared__ bf16 lA[128 * 32];
  __shared__ bf16 lB[64 * 32];

  const int t    = threadIdx.x;
  const int wave = t >> 6;
  const int lane = t & 63;
  const int quad = lane >> 4;
  const int l16  = lane & 15;
  const int bm = blockIdx.x;
  const int bn = blockIdx.y;
  const int wm = wave * 32;

  const int srow = t >> 2;
  const int scol = (t & 3) * 8;
  const bf16* gA = A  + (size_t)(bm * 128 + srow) * D_ + scol;
  const bf16* gB = Bw + (size_t)(bn * 64 + srow) * D_ + scol;

  f32x4 acc[2][4] = {};

  for (int k0 = 0; k0 < D_; k0 += 32) {
    __syncthreads();
    gload_lds16(gA,                   (char*)lA + wave * 1024);
    gload_lds16(gA + (size_t)64 * D_, (char*)lA + 4096 + wave * 1024);
    gload_lds16(gB,                   (char*)lB + wave * 1024);
    __syncthreads();

    bf16x8 af[2], bfr[4];
#pragma unroll
    for (int i = 0; i < 2; ++i)
      af[i]  = *(const bf16x8*)(lA + (wm + i * 16 + l16) * 32 + quad * 8);
#pragma unroll
    for (int i = 0; i < 4; ++i)
      bfr[i] = *(const bf16x8*)(lB + (i * 16 + l16) * 32 + quad * 8);
#pragma unroll
    for (int mi = 0; mi < 2; ++mi)
#pragma unroll
      for (int ni = 0; ni < 4; ++ni)
        acc[mi][ni] = __builtin_amdgcn_mfma_f32_16x16x32_bf16(
            af[mi], bfr[ni], acc[mi][ni], 0, 0, 0);

    gA += 32;
    gB += 32;
  }

  float bv[4];
#pragma unroll
  for (int ni = 0; ni < 4; ++ni)
    bv[ni] = bias[bn * 64 + ni * 16 + l16];
#pragma unroll
  for (int mi = 0; mi < 2; ++mi) {
#pragma unroll
    for (int ni = 0; ni < 4; ++ni) {
      const int col = bn * 64 + ni * 16 + l16;
#pragma unroll
      for (int r = 0; r < 4; ++r) {
        const int row = bm * 128 + wm + mi * 16 + quad * 4 + r;
        C[(size_t)row * D_ + col] = acc[mi][ni][r] + bv[ni];
      }
    }
  }
}

// ---------------------------------------------------------------------------
// FALLBACK QKV projection (ws < 16 MiB): fp32 weights, QSCALE_ fold on Q.
// ---------------------------------------------------------------------------
__global__ __launch_bounds__(256, 2)
void gemm_qkv_kernel(const float* __restrict__ Aq, const float* __restrict__ Ak,
                     const float* __restrict__ Av, const float* __restrict__ Wq,
                     const float* __restrict__ Wk, const float* __restrict__ Wv,
                     bf16* __restrict__ Cq, bf16* __restrict__ Ck,
                     bf16* __restrict__ Cv)
{
  __shared__ bf16 lA[128 * 32];
  __shared__ bf16 lB[128 * 32];

  const int sel = blockIdx.y >> 3;
  const int bn  = blockIdx.y & 7;
  const float* A  = sel == 0 ? Aq : (sel == 1 ? Ak : Av);
  const float* Bw = sel == 0 ? Wq : (sel == 1 ? Wk : Wv);
  bf16*        C  = sel == 0 ? Cq : (sel == 1 ? Ck : Cv);
  const float scale = sel == 0 ? QSCALE_ : 1.0f;

  const int t    = threadIdx.x;
  const int wave = t >> 6;
  const int lane = t & 63;
  const int quad = lane >> 4;
  const int l16  = lane & 15;
  const int bm = blockIdx.x;
  const int wm = (wave >> 1) * 64;
  const int wn = (wave & 1) * 64;

  const int srow = t >> 2;
  const int scol = (t & 3) * 8;
  const float* gA = A  + (size_t)(bm * 128 + srow) * D_ + scol;
  const float* gB = Bw + (size_t)(bn * 128 + srow) * D_ + scol;

  f32x4 acc[4][4] = {};

  for (int k0 = 0; k0 < D_; k0 += 32) {
    const bf16x8 a0 = load8(gA);
    const bf16x8 a1 = load8(gA + (size_t)64 * D_);
    const bf16x8 b0 = load8(gB);
    const bf16x8 b1 = load8(gB + (size_t)64 * D_);

    __syncthreads();
    *(bf16x8*)(lA + srow * 32 + scol)        = a0;
    *(bf16x8*)(lA + (srow + 64) * 32 + scol) = a1;
    *(bf16x8*)(lB + srow * 32 + scol)        = b0;
    *(bf16x8*)(lB + (srow + 64) * 32 + scol) = b1;
    __syncthreads();

    bf16x8 af[4], bfr[4];
#pragma unroll
    for (int i = 0; i < 4; ++i) {
      af[i]  = *(const bf16x8*)(lA + (wm + i * 16 + l16) * 32 + quad * 8);
      bfr[i] = *(const bf16x8*)(lB + (wn + i * 16 + l16) * 32 + quad * 8);
    }
#pragma unroll
    for (int mi = 0; mi < 4; ++mi)
#pragma unroll
      for (int ni = 0; ni < 4; ++ni)
        acc[mi][ni] = __builtin_amdgcn_mfma_f32_16x16x32_bf16(
            af[mi], bfr[ni], acc[mi][ni], 0, 0, 0);

    gA += 32;
    gB += 32;
  }

#pragma unroll
  for (int mi = 0; mi < 4; ++mi) {
#pragma unroll
    for (int ni = 0; ni < 4; ++ni) {
      const int col = bn * 128 + wn + ni * 16 + l16;
#pragma unroll
      for (int r = 0; r < 4; ++r) {
        const int row = bm * 128 + wm + mi * 16 + quad * 4 + r;
        C[(size_t)row * D_ + col] = (bf16)(acc[mi][ni][r] * scale);
      }
    }
  }
}

// ---------------------------------------------------------------------------
// FALLBACK output projection (ws < 16 MiB): fp32 weights. Tile 128x64.
// ---------------------------------------------------------------------------
__global__ __launch_bounds__(256, 2)
void gemm_out_kernel(const bf16* __restrict__ A, const float* __restrict__ Bw,
                     const float* __restrict__ bias, float* __restrict__ C)
{
  __shared__ bf16 lA[128 * 32];
  __shared__ bf16 lB[64 * 32];

  const int t    = threadIdx.x;
  const int wave = t >> 6;
  const int lane = t & 63;
  const int quad = lane >> 4;
  const int l16  = lane & 15;
  const int bm = blockIdx.x;
  const int bn = blockIdx.y;
  const int wm = wave * 32;

  const int srow = t >> 2;
  const int scol = (t & 3) * 8;
  const bf16*  gA = A  + (size_t)(bm * 128 + srow) * D_ + scol;
  const float* gB = Bw + (size_t)(bn * 64 + srow) * D_ + scol;

  f32x4 acc[2][4] = {};

  for (int k0 = 0; k0 < D_; k0 += 32) {
    const bf16x8 a0 = load8(gA);
    const bf16x8 a1 = load8(gA + (size_t)64 * D_);
    const bf16x8 b0 = load8(gB);

    __syncthreads();
    *(bf16x8*)(lA + srow * 32 + scol)        = a0;
    *(bf16x8*)(lA + (srow + 64) * 32 + scol) = a1;
    *(bf16x8*)(lB + srow * 32 + scol)        = b0;
    __syncthreads();

    bf16x8 af[2], bfr[4];
#pragma unroll
    for (int i = 0; i < 2; ++i)
      af[i]  = *(const bf16x8*)(lA + (wm + i * 16 + l16) * 32 + quad * 8);
#pragma unroll
    for (int i = 0; i < 4; ++i)
      bfr[i] = *(const bf16x8*)(lB + (i * 16 + l16) * 32 + quad * 8);
#pragma unroll
    for (int mi = 0; mi < 2; ++mi)
#pragma unroll
      for (int ni = 0; ni < 4; ++ni)
        acc[mi][ni] = __builtin_amdgcn_mfma_f32_16x16x32_bf16(
            af[mi], bfr[ni], acc[mi][ni], 0, 0, 0);

    gA += 32;
    gB += 32;
  }

  float bv[4];
#pragma unroll
  for (int ni = 0; ni < 4; ++ni)
    bv[ni] = bias[bn * 64 + ni * 16 + l16];
#pragma unroll
  for (int mi = 0; mi < 2; ++mi) {
#pragma unroll
    for (int ni = 0; ni < 4; ++ni) {
      const int col = bn * 64 + ni * 16 + l16;
#pragma unroll
      for (int r = 0; r < 4; ++r) {
        const int row = bm * 128 + wm + mi * 16 + quad * 4 + r;
        C[(size_t)row * D_ + col] = acc[mi][ni][r] + bv[ni];
      }
    }
  }
}

// ---------------------------------------------------------------------------
// Flash attention v9 (FINAL, round-16 verified best total 206.6 us):
// v8 per-wave code with 256 Q-ROWS PER BLOCK (8 waves, 512 threads). Each
// staged K/V tile serves 256 q-rows; K/V L2 traffic and LDS staging per
// q-row halve vs v8. Statistically tied with v8 (206.9/209.8); kept as the
// best-measured-total configuration.
//  - In-register P via cvt_pk + permlane butterfly (no lP buffer/fence).
//  - SWAPPED QK^T; per-lane denominator; reg prefetch of next K/V tile.
// grid (8, 32) = 256 blocks = 1/CU; LDS 54 KiB.
// ---------------------------------------------------------------------------
__global__ __launch_bounds__(512, 1)
void attn_kernel(const bf16* Q, const bf16* __restrict__ K,
                 const bf16* __restrict__ V, bf16* O)
{
  __shared__ bf16 lQ[256 * 72];
  __shared__ bf16 lK[64 * 72];
  __shared__ bf16 lVT[64 * 72];

  const int t    = threadIdx.x;
  const int wave = t >> 6;          // 0..7
  const int lane = t & 63;
  const int quad = lane >> 4;
  const int l16  = lane & 15;

  // XCD swizzle: 256 blocks; flat bits [2:0]=xcd, [5:3]=qt, [7:6]=head-in-xcd
  const int flat = blockIdx.y * 8 + blockIdx.x;
  const int qt   = (flat >> 3) & 7;
  const int bh   = (flat & 7) * 4 + (flat >> 6);
  const size_t headoff =
      (size_t)(bh >> 4) * ((size_t)S_ * D_) + (size_t)(bh & 15) * HD_;

  const bf16* Kb = K + headoff;
  const bf16* Vb = V + headoff;

  // ---- stage Q tile (256 rows)
  const int sr  = t >> 3;          // 0..63
  const int scx = (t & 7) * 8;
#pragma unroll
  for (int i = 0; i < 4; ++i) {
    const bf16x8 qv =
        *(const bf16x8*)(Q + headoff + (size_t)(qt * 256 + sr + 64 * i) * D_ + scx);
    *(bf16x8*)(lQ + (sr + 64 * i) * 72 + scx) = qv;
  }
  __syncthreads();

  // Q fragments (B-operand of swapped QK^T): lane's l16 picks the q-row.
  bf16x8 qf[2][2];
#pragma unroll
  for (int m = 0; m < 2; ++m)
#pragma unroll
    for (int ks = 0; ks < 2; ++ks)
      qf[m][ks] = *(const bf16x8*)(lQ + (wave * 32 + m * 16 + l16) * 72 +
                                   (ks * 4 + quad) * 8);

  f32x4 acco[2][4] = {};
  float den[2] = {0.f, 0.f};

  const int dp = t & 31;    // d-pair index: columns 2dp, 2dp+1
  const int kg = t >> 5;    // key group 0..15: keys kg*4 .. kg*4+3

  // ---- prefetch registers
  bf16x8 pk0;
  unsigned int pv[4];
  {
    const bf16* kb = Kb + (size_t)sr * D_ + scx;        // kt = 0, 64x64 exact
    pk0 = load8(kb);
    const bf16* vb = Vb + (size_t)(kg * 4) * D_ + 2 * dp;
#pragma unroll
    for (int j = 0; j < 4; ++j)
      pv[j] = *(const unsigned int*)(vb + (size_t)j * D_);
  }

  for (int kt = 0; kt < S_ / 64; ++kt) {
    __syncthreads();   // prev iteration's lK/lVT reads done

    // ---- commit prefetched K tile (one b128 per thread)
    *(bf16x8*)(lK + sr * 72 + scx) = pk0;
    // ---- commit prefetched V (transposed): rows 2dp, 2dp+1, keys kg*4..+3
    {
      u16x4v w0, w1;
#pragma unroll
      for (int j = 0; j < 4; ++j) {
        w0[j] = (unsigned short)(pv[j] & 0xffffu);
        w1[j] = (unsigned short)(pv[j] >> 16);
      }
      *(u16x4v*)(lVT + (2 * dp) * 72 + kg * 4)     = w0;
      *(u16x4v*)(lVT + (2 * dp + 1) * 72 + kg * 4) = w1;
    }
    __syncthreads();   // staging visible

    // ---- prefetch next iteration (in flight during compute)
    if (kt + 1 < S_ / 64) {
      const bf16* kb = Kb + (size_t)((kt + 1) * 64 + sr) * D_ + scx;
      pk0 = load8(kb);
      const bf16* vb = Vb + (size_t)((kt + 1) * 64 + kg * 4) * D_ + 2 * dp;
#pragma unroll
      for (int j = 0; j < 4; ++j)
        pv[j] = *(const unsigned int*)(vb + (size_t)j * D_);
    }

    // ---- S^T = K Q^T  (Q pre-scaled; kf reused across both m-halves)
    f32x4 sc[2][4] = {};
#pragma unroll
    for (int nt = 0; nt < 4; ++nt) {
#pragma unroll
      for (int ks = 0; ks < 2; ++ks) {
        const bf16x8 kf =
            *(const bf16x8*)(lK + (nt * 16 + l16) * 72 + (ks * 4 + quad) * 8);
#pragma unroll
        for (int m = 0; m < 2; ++m)
          sc[m][nt] = __builtin_amdgcn_mfma_f32_16x16x32_bf16(
              kf, qf[m][ks], sc[m][nt], 0, 0, 0);
      }
    }

    // ---- p = exp2(s); pack to bf16 words; permlane butterfly -> pf in regs
    bf16x8 pf[2][2];
#pragma unroll
    for (int m = 0; m < 2; ++m) {
      unsigned int W[4][2];      // [nt][j], fully static indexing
#pragma unroll
      for (int nt = 0; nt < 4; ++nt) {
        const float p0 = __builtin_amdgcn_exp2f(sc[m][nt][0]);
        const float p1 = __builtin_amdgcn_exp2f(sc[m][nt][1]);
        const float p2 = __builtin_amdgcn_exp2f(sc[m][nt][2]);
        const float p3 = __builtin_amdgcn_exp2f(sc[m][nt][3]);
        den[m] += (p0 + p1) + (p2 + p3);
        asm("v_cvt_pk_bf16_f32 %0, %1, %2" : "=v"(W[nt][0]) : "v"(p0), "v"(p1));
        asm("v_cvt_pk_bf16_f32 %0, %1, %2" : "=v"(W[nt][1]) : "v"(p2), "v"(p3));
      }
#pragma unroll
      for (int ks = 0; ks < 2; ++ks) {
        unsigned int r0 = W[2 * ks][0], s0 = W[2 * ks + 1][0];
        unsigned int r1 = W[2 * ks][1], s1 = W[2 * ks + 1][1];
        asm("v_permlane32_swap_b32 %0, %1" : "+v"(r0), "+v"(s0));
        asm("v_permlane16_swap_b32 %0, %1" : "+v"(r0), "+v"(s0));
        asm("v_permlane32_swap_b32 %0, %1" : "+v"(r1), "+v"(s1));
        asm("v_permlane16_swap_b32 %0, %1" : "+v"(r1), "+v"(s1));
        const u32x4 pw = {r0, r1, s0, s1};   // words w0,w1,w2,w3
        pf[m][ks] = __builtin_bit_cast(bf16x8, pw);
      }
    }

    // ---- O += P V  (vf reused across both m-halves; pf from registers)
#pragma unroll
    for (int dt = 0; dt < 4; ++dt) {
#pragma unroll
      for (int ks = 0; ks < 2; ++ks) {
        const bf16x8 vf =
            *(const bf16x8*)(lVT + (dt * 16 + l16) * 72 + (ks * 4 + quad) * 8);
#pragma unroll
        for (int m = 0; m < 2; ++m)
          acco[m][dt] = __builtin_amdgcn_mfma_f32_16x16x32_bf16(
              pf[m][ks], vf, acco[m][dt], 0, 0, 0);
      }
    }
  }

  // ---- epilogue: finish denominator (sum the 4 key-quads), normalize, store
#pragma unroll
  for (int m = 0; m < 2; ++m) {
    den[m] += __shfl_xor(den[m], 16);
    den[m] += __shfl_xor(den[m], 32);
  }
#pragma unroll
  for (int m = 0; m < 2; ++m) {
#pragma unroll
    for (int r = 0; r < 4; ++r) {
      const float rd  = 1.f / __shfl(den[m], quad * 4 + r);
      const int   row = qt * 256 + wave * 32 + m * 16 + quad * 4 + r;
#pragma unroll
      for (int dt = 0; dt < 4; ++dt)
        O[headoff + (size_t)row * D_ + dt * 16 + l16] =
            (bf16)(acco[m][dt][r] * rd);
    }
  }
}

// ---------------------------------------------------------------------------
// Tiers:
//  ws >= 40 MiB: conv (W + q/k/v -> bf16), pure-bf16 QKV GEMM (128x128),
//                attn v9 (256-row blocks, in-register P), out (128x64).
//                ws: Wb[0,8MiB) Qp[8,16) Aq[16,24) Ak[24,32) Av[32,40).
//  ws >= 16 MiB: wconv + fp32-A reg-prefetch QKV, attn, out.
//  else:         fp32-weight fallback.
// K'/V' live in d_out (bf16 view); final GEMM overwrites d_out with fp32.
// ---------------------------------------------------------------------------
extern "C" void kernel_launch(void* const* d_in, const int* in_sizes, int n_in,
                              void* d_out, int out_size, void* d_ws, size_t ws_size,
                              hipStream_t stream)
{
  const float* q  = (const float*)d_in[0];
  const float* k  = (const float*)d_in[1];
  const float* v  = (const float*)d_in[2];
  const float* Wq = (const float*)d_in[3];
  const float* Wk = (const float*)d_in[4];
  const float* Wv = (const float*)d_in[5];
  const float* Wo = (const float*)d_in[6];
  const float* bo = (const float*)d_in[7];
  float* outf = (float*)d_out;
  bf16*  outs = (bf16*)d_out;
  bf16*  wsb  = (bf16*)d_ws;

  const size_t MD = (size_t)B_ * S_ * D_;   // 4 Mi elements

  dim3 blk(256);
  dim3 blka(512);
  dim3 gqkv(B_ * S_ / 128, 24);
  dim3 gattn(S_ / 256, B_ * H_);
  dim3 gout(B_ * S_ / 128, D_ / 64);

  bf16* Kp = outs;          // d_out [0, 8Mi)
  bf16* Vp = outs + MD;     // d_out [8Mi, 16Mi)

  if (ws_size >= (size_t)40 << 20) {
    bf16* Wb = wsb;            // [0, 4Mi el): Wq|Wk|Wv|Wo bf16
    bf16* Qp = wsb + MD;       // [4Mi, 8Mi el): Q' -> ctx in place
    bf16* Ab = wsb + 2 * MD;   // [8Mi, 20Mi el): q|k|v bf16

    conv_kernel<<<16384, blk, 0, stream>>>(Wq, Wk, Wv, Wo, q, k, v, wsb);
    gemm_qkv3_kernel<<<gqkv, blk, 0, stream>>>(Ab, Wb, Qp, Kp, Vp);
    attn_kernel<<<gattn, blka, 0, stream>>>(Qp, Kp, Vp, Qp);
    gemm_out_b_kernel<<<gout, blk, 0, stream>>>(Qp, Wb + 3 * ((size_t)1 << 20),
                                                bo, outf);
  } else if (ws_size >= (size_t)16 << 20) {
    bf16* Wb = wsb;          // 4 Mi el = 8 MiB: Wq|Wk|Wv|Wo bf16
    bf16* Qp = wsb + MD;     // ws [8, 16 MiB); becomes Ctx in place

    wconv_kernel<<<4096, blk, 0, stream>>>(Wq, Wk, Wv, Wo, Wb);
    gemm_qkv_b_kernel<<<gqkv, blk, 0, stream>>>(q, k, v, Wb, Qp, Kp, Vp);
    attn_kernel<<<gattn, blka, 0, stream>>>(Qp, Kp, Vp, Qp);
    gemm_out_b_kernel<<<gout, blk, 0, stream>>>(Qp, Wb + 3 * ((size_t)1 << 20),
                                                bo, outf);
  } else {
    bf16* Qp = wsb;          // ws [0, 8 MiB); becomes Ctx in place

    gemm_qkv_kernel<<<gqkv, blk, 0, stream>>>(q, k, v, Wq, Wk, Wv,
                                              Qp, Kp, Vp);
    attn_kernel<<<gattn, blka, 0, stream>>>(Qp, Kp, Vp, Qp);
    gemm_out_kernel<<<gout, blk, 0, stream>>>(Qp, Wo, bo, outf);
  }
}